// Round 8
// baseline (116.631 us; speedup 1.0000x reference)
//
#include <hip/hip_runtime.h>

// Deformable conv (K=3, stride=1, pad=1, dil=1), N=8, Cin=Cout=128, H=W=64.
// v9: SPLIT the fused deform kernel into two throughput-bound streaming kernels.
//   Evidence: v0-v8 all plateau at 40-50us with every pipe <25% busy — one workgroup
//   per (n,ho) runs 9 taps of gather->blend->MFMA as a dependent chain, and the
//   problem yields only 2-4K waves, so exposed latency dominates regardless of
//   sync structure (barrier / flags / asm pinning all tried).
//   - sample_k: grid 4608 x 512thr = 36864 waves (144/CU queued): per thread load
//     dy/dx, gather 4 corners x 16ch, blend, store 32B to S[n][ho][wo][tap][ch]
//     (75.5MB bf16, L3-resident). No LDS, no barriers, no MFMA -> pure TLP hides
//     all gather latency.
//   - gemm_k: v4/v7's VERIFIED MFMA structure (grid 512, 4 waves, wave 64wo x 32co,
//     acc[4][2]); A staged per tap from S (contiguous 256B rows, no gathers);
//     B-frags from the v7-verified fragment-contiguous wt2 (1KB coalesced loads);
//     dbuf samp LDS, one barrier/tap. Per tap: 4 loads + LDS write + 32 MFMA.
//   - no spin flags / LDS atomics anywhere (v8's profiled 30ms dispatch = metastable).
//   - keeps: XCD-local n=bid&7 everywhere, cvt_pk_bf16, padded SROW.
// ws: xt 8MB @0; wt2 288KB @8388608; S 75.5MB @8683520. Fully rewritten each launch.

#define H  64
#define W  64
#define CIN 128
#define COUT 128
#define NB 8
#define KK 9
#define SROW (CIN + 8)

typedef short bf16x8 __attribute__((ext_vector_type(8)));
typedef float f32x4  __attribute__((ext_vector_type(4)));

__device__ __forceinline__ unsigned short f2bf(float f) {
    unsigned u = __builtin_bit_cast(unsigned, f);
    u += 0x7FFFu + ((u >> 16) & 1u);          // round-nearest-even
    return (unsigned short)(u >> 16);
}
__device__ __forceinline__ unsigned cvt_pk_bf16(float lo, float hi) {
    unsigned r;
    asm("v_cvt_pk_bf16_f32 %0, %1, %2" : "=v"(r) : "v"(lo), "v"(hi));
    return r;                                  // low16 = bf16(lo), high16 = bf16(hi), RNE
}
__device__ __forceinline__ float lo_f(unsigned u) { return __builtin_bit_cast(float, u << 16); }
__device__ __forceinline__ float hi_f(unsigned u) { return __builtin_bit_cast(float, u & 0xFFFF0000u); }

// Merged prep: blocks [0, NB*H) transpose x (NCHW fp32 -> NHWC bf16), XCD-local (n = b&7);
// blocks [NB*H, NB*H+576): weight fp32 [co][c][kk] -> wt2 fragment-contiguous bf16:
//   wt2 flat idx = ((((kk*4 + c4)*2 + nt)*4 + ct)*64 + lm*4 + lq)*8 + e
//   where co = c4*32 + nt*16 + lm, ch = ct*32 + lq*8 + e.   [verified in round 6]
__global__ void prep_all(const float* __restrict__ x, const float* __restrict__ w,
                         unsigned short* __restrict__ xt, unsigned short* __restrict__ wt) {
    int b = blockIdx.x;
    int t = threadIdx.x;
    if (b >= NB * H) {                        // ---- weight part ----
        int idx = (b - NB * H) * 256 + t;
        if (idx < KK * COUT * CIN) {
            int e  = idx & 7;
            int lq = (idx >> 3) & 3;
            int lm = (idx >> 5) & 15;
            int ct = (idx >> 9) & 3;
            int nt = (idx >> 11) & 1;
            int c4 = (idx >> 12) & 3;
            int kk = idx >> 14;
            int co = (c4 << 5) + (nt << 4) + lm;
            int ch = (ct << 5) + (lq << 3) + e;
            wt[idx] = f2bf(w[(co * CIN + ch) * KK + kk]);
        }
        return;
    }
    // ---- x-transpose part: one (n,y) row per block; n = b&7 matches XCD map ----
    __shared__ float tile[CIN][W + 4];
    int n = b & 7, y = b >> 3;
    const float* src = x + ((size_t)n * CIN * H + y) * W;
    #pragma unroll
    for (int it = 0; it < 8; ++it) {
        int idx = it * 256 + t;               // 0..2047 float4s
        int c  = idx >> 4;
        int x4 = (idx & 15) << 2;
        int xs = (x4 + ((c >> 5) << 4)) & 63; // rotate-swizzle per 32-ch group
        *(float4*)&tile[c][xs] = *(const float4*)(src + (size_t)c * H * W + x4);
    }
    __syncthreads();
    int xp = t >> 2;                          // x position 0..63
    int cbch = (t & 3) << 5;                  // channel base (32-ch chunk)
    int xr = (xp + ((cbch >> 5) << 4)) & 63;
    unsigned short* dst = xt + (((size_t)(n * H + y) * W + xp) * CIN + cbch);
    unsigned rr[16];
    #pragma unroll
    for (int i = 0; i < 16; ++i)
        rr[i] = cvt_pk_bf16(tile[cbch + 2 * i][xr], tile[cbch + 2 * i + 1][xr]);
    #pragma unroll
    for (int i = 0; i < 4; ++i)
        ((uint4*)dst)[i] = make_uint4(rr[4*i], rr[4*i+1], rr[4*i+2], rr[4*i+3]);
}

struct GatherCtx {
    const unsigned short *c00, *c01, *c10, *c11;
    float w00, w01, w10, w11;
};

__device__ __forceinline__ GatherCtx gather_setup(float dy, float dx, int ho, int wo, int kk,
                                                  const unsigned short* xbase) {
    GatherCtx g;
    float py = (float)(ho - 1 + kk / 3) + dy;
    float px = (float)(wo - 1 + kk % 3) + dx;
    float y0f = floorf(py), x0f = floorf(px);
    float wy1 = py - y0f, wx1 = px - x0f;
    float wy0 = 1.f - wy1, wx0 = 1.f - wx1;
    int y0 = (int)y0f, x0 = (int)x0f;
    int y1 = y0 + 1, x1 = x0 + 1;
    bool vy0 = (unsigned)y0 < (unsigned)H, vy1 = (unsigned)y1 < (unsigned)H;
    bool vx0 = (unsigned)x0 < (unsigned)W, vx1 = (unsigned)x1 < (unsigned)W;
    g.w00 = (vy0 && vx0) ? wy0 * wx0 : 0.f;
    g.w01 = (vy0 && vx1) ? wy0 * wx1 : 0.f;
    g.w10 = (vy1 && vx0) ? wy1 * wx0 : 0.f;
    g.w11 = (vy1 && vx1) ? wy1 * wx1 : 0.f;
    int yc0 = min(max(y0, 0), H - 1), yc1 = min(max(y1, 0), H - 1);
    int xc0 = min(max(x0, 0), W - 1), xc1 = min(max(x1, 0), W - 1);
    const unsigned short* r0 = xbase + (size_t)yc0 * W * CIN;
    const unsigned short* r1 = xbase + (size_t)yc1 * W * CIN;
    g.c00 = r0 + xc0 * CIN;  g.c01 = r0 + xc1 * CIN;
    g.c10 = r1 + xc0 * CIN;  g.c11 = r1 + xc1 * CIN;
    return g;
}

// ---- sample kernel: one block = (n, tap, ho); 512 thr -> (pos = t>>3, 16ch chunk) ----
__global__ __launch_bounds__(512, 2) void sample_k(
        const float* __restrict__ offs, const unsigned short* __restrict__ xt,
        unsigned short* __restrict__ S) {
    int b = blockIdx.x;
    int n = b & 7;
    int r = b >> 3;                 // 0..575
    int tap = r >> 6;               // 0..8
    int ho = r & 63;
    int t = threadIdx.x;
    int pos = t >> 3;               // wo 0..63
    int cb = (t & 7) << 4;          // 16-channel chunk base

    const float* offp = offs + ((size_t)(n * 2 * KK + 2 * tap) * H + ho) * W + pos;
    float dy = offp[0];
    float dx = offp[(size_t)H * W];

    GatherCtx g = gather_setup(dy, dx, ho, pos, tap, xt + (size_t)n * H * W * CIN + cb);

    uint4 gv[8];
    #pragma unroll
    for (int j = 0; j < 2; ++j) {   // 2 x 8-channel sub-chunks
        gv[4*j+0] = *(const uint4*)(g.c00 + 8*j);
        gv[4*j+1] = *(const uint4*)(g.c01 + 8*j);
        gv[4*j+2] = *(const uint4*)(g.c10 + 8*j);
        gv[4*j+3] = *(const uint4*)(g.c11 + 8*j);
    }
    unsigned rr[8];
    #pragma unroll
    for (int j = 0; j < 2; ++j) {
        const unsigned* a0 = (const unsigned*)&gv[4*j+0];
        const unsigned* a1 = (const unsigned*)&gv[4*j+1];
        const unsigned* a2 = (const unsigned*)&gv[4*j+2];
        const unsigned* a3 = (const unsigned*)&gv[4*j+3];
        #pragma unroll
        for (int i = 0; i < 4; ++i) {
            float v0 = g.w00*lo_f(a0[i]) + g.w01*lo_f(a1[i]) + g.w10*lo_f(a2[i]) + g.w11*lo_f(a3[i]);
            float v1 = g.w00*hi_f(a0[i]) + g.w01*hi_f(a1[i]) + g.w10*hi_f(a2[i]) + g.w11*hi_f(a3[i]);
            rr[4*j+i] = cvt_pk_bf16(v0, v1);
        }
    }
    // S[n][ho][wo][tap][ch]: K-dim (tap,ch) contiguous per output row
    size_t so = ((((size_t)(n * H + ho) * W + pos) * KK + tap) << 7) + cb;
    *(uint4*)(S + so)     = make_uint4(rr[0], rr[1], rr[2], rr[3]);
    *(uint4*)(S + so + 8) = make_uint4(rr[4], rr[5], rr[6], rr[7]);
}

// ---- GEMM kernel: one block = (n, ho); 256 thr = 4 waves; wave = 64 wo x 32 co ----
__global__ __launch_bounds__(256, 2) void gemm_k(
        const unsigned short* __restrict__ S, const unsigned short* __restrict__ wt,
        float* __restrict__ out) {
    __shared__ __attribute__((aligned(16))) unsigned short samp[2][64][SROW];  // 34,816 B

    int b = blockIdx.x;
    int n = b & 7, ho = b >> 3;
    int t = threadIdx.x;
    int lane = t & 63, wv = t >> 6;
    int lm = lane & 15, lq = lane >> 4;
    int cobase = wv << 5;
    int slot = (lm << 2) + lq;

    f32x4 acc[4][2];
    #pragma unroll
    for (int mt = 0; mt < 4; ++mt)
        #pragma unroll
        for (int nt = 0; nt < 2; ++nt) acc[mt][nt] = f32x4{0.f, 0.f, 0.f, 0.f};

    // staging map: thread -> (pos, 32ch segment of the current tap)
    int pos = t >> 2;
    int seg = t & 3;
    const unsigned short* srow = S + ((((size_t)(n * H + ho) * W + pos) * KK) << 7) + (seg << 5);
    const unsigned short* wvbase = wt + ((size_t)wv << 12) + (slot << 3);

    // prologue: stage tap 0
    {
        uint4 st[4];
        #pragma unroll
        for (int i = 0; i < 4; ++i) st[i] = *(const uint4*)(srow + (i << 3));
        unsigned short* ld = &samp[0][pos][seg << 5];
        #pragma unroll
        for (int i = 0; i < 4; ++i) *(uint4*)(ld + (i << 3)) = st[i];
    }
    __syncthreads();

    for (int tap = 0; tap < KK; ++tap) {
        uint4 nx[4];
        if (tap < KK - 1) {
            const unsigned short* sr = srow + ((size_t)(tap + 1) << 7);
            #pragma unroll
            for (int i = 0; i < 4; ++i) nx[i] = *(const uint4*)(sr + (i << 3));
        }
        // B-frags for this tap (fragment-contiguous wt2: 1KB coalesced per frag)
        const unsigned short* wkb = wvbase + ((size_t)tap << 14);
        bf16x8 bW[2][4];
        #pragma unroll
        for (int nt = 0; nt < 2; ++nt)
            #pragma unroll
            for (int ct = 0; ct < 4; ++ct)
                bW[nt][ct] = *(const bf16x8*)(wkb + (((nt << 2) + ct) << 9));

        #pragma unroll
        for (int ct = 0; ct < 4; ++ct) {
            bf16x8 a[4];
            #pragma unroll
            for (int mt = 0; mt < 4; ++mt)
                a[mt] = *(const bf16x8*)&samp[tap & 1][lm + (mt << 4)][(ct << 5) + (lq << 3)];
            #pragma unroll
            for (int mt = 0; mt < 4; ++mt) {
                acc[mt][0] = __builtin_amdgcn_mfma_f32_16x16x32_bf16(a[mt], bW[0][ct], acc[mt][0], 0, 0, 0);
                acc[mt][1] = __builtin_amdgcn_mfma_f32_16x16x32_bf16(a[mt], bW[1][ct], acc[mt][1], 0, 0, 0);
            }
        }
        if (tap < KK - 1) {
            unsigned short* ld = &samp[(tap + 1) & 1][pos][seg << 5];
            #pragma unroll
            for (int i = 0; i < 4; ++i) *(uint4*)(ld + (i << 3)) = nx[i];
        }
        __syncthreads();
    }

    // epilogue: D[m = mt*16 + lq*4 + j][n = lm] -> out[n][co][ho][wo], float4 over wo
    #pragma unroll
    for (int mt = 0; mt < 4; ++mt) {
        int wob = (mt << 4) + (lq << 2);
        #pragma unroll
        for (int nt = 0; nt < 2; ++nt) {
            int co = cobase + (nt << 4) + lm;
            *(f32x4*)(out + (((size_t)(n * COUT + co) * H + ho) * W + wob)) = acc[mt][nt];
        }
    }
}

extern "C" void kernel_launch(void* const* d_in, const int* in_sizes, int n_in,
                              void* d_out, int out_size, void* d_ws, size_t ws_size,
                              hipStream_t stream) {
    const float* x      = (const float*)d_in[0];   // (8,128,64,64)
    const float* offset = (const float*)d_in[1];   // (8,18,64,64)
    const float* weight = (const float*)d_in[2];   // (128,128,3,3)
    float* out = (float*)d_out;

    unsigned short* xt = (unsigned short*)d_ws;                                  // 8 MB
    unsigned short* wt = (unsigned short*)((char*)d_ws + 8388608);               // 288 KB
    unsigned short* S  = (unsigned short*)((char*)d_ws + 8683520);               // 75.5 MB

    int wblocks = (KK * COUT * CIN + 255) / 256;   // 576
    hipLaunchKernelGGL(prep_all, dim3(NB * H + wblocks), dim3(256), 0, stream,
                       x, weight, xt, wt);
    hipLaunchKernelGGL(sample_k, dim3(NB * KK * H), dim3(512), 0, stream,
                       offset, xt, S);
    hipLaunchKernelGGL(gemm_k, dim3(NB * H), dim3(256), 0, stream,
                       S, wt, out);
}

// Round 9
// 109.263 us; speedup vs baseline: 1.0674x; 1.0674x over previous
//
#include <hip/hip_runtime.h>

// Deformable conv (K=3, stride=1, pad=1, dil=1), N=8, Cin=Cout=128, H=W=64.
// v10: FUSE sample+gemm into one kernel — key insight from v9: gemm's A-staging
//   thread reads back exactly the bytes the SAME thread wrote in sampling (S is a
//   per-thread L2 spill buffer, no cross-block dep). So:
//   - phase A (per block (n,ho), 512 thr): all 9 taps gather->blend->store-to-S with
//     ZERO barriers / ZERO MFMA interleaved -> the 9-tap latency chain flows freely,
//     covered by 16 waves/CU (v0-v7's plateau came from chopping this chain with
//     per-tap barriers; v9 fixed it but paid an extra launch + cross-kernel sync).
//   - phase B: v9's verified GEMM, 8-wave variant (wave = 64 pos x 16 co, acc[4]);
//     A-reads are own-data L2 hits; B-frags from verified fragment-contiguous wt2;
//     dbuf LDS samp, 1 barrier/tap.
//   - 3 dispatches total (prep_all, fused_main) vs v9's 4.
//   - keeps: XCD-local n=bid&7, cvt_pk_bf16, padded SROW, no spin-flags.
// ws: xt 8MB @0; wt2 288KB @8388608; S 75.5MB @8683520. Fully rewritten each launch.

#define H  64
#define W  64
#define CIN 128
#define COUT 128
#define NB 8
#define KK 9
#define SROW (CIN + 8)

typedef short bf16x8 __attribute__((ext_vector_type(8)));
typedef float f32x4  __attribute__((ext_vector_type(4)));

__device__ __forceinline__ unsigned short f2bf(float f) {
    unsigned u = __builtin_bit_cast(unsigned, f);
    u += 0x7FFFu + ((u >> 16) & 1u);          // round-nearest-even
    return (unsigned short)(u >> 16);
}
__device__ __forceinline__ unsigned cvt_pk_bf16(float lo, float hi) {
    unsigned r;
    asm("v_cvt_pk_bf16_f32 %0, %1, %2" : "=v"(r) : "v"(lo), "v"(hi));
    return r;                                  // low16 = bf16(lo), high16 = bf16(hi), RNE
}
__device__ __forceinline__ float lo_f(unsigned u) { return __builtin_bit_cast(float, u << 16); }
__device__ __forceinline__ float hi_f(unsigned u) { return __builtin_bit_cast(float, u & 0xFFFF0000u); }

// Merged prep: blocks [0, NB*H) transpose x (NCHW fp32 -> NHWC bf16), XCD-local (n = b&7);
// blocks [NB*H, NB*H+576): weight fp32 [co][c][kk] -> wt2 fragment-contiguous bf16:
//   wt2 flat idx = ((((kk*4 + c4)*2 + nt)*4 + ct)*64 + lm*4 + lq)*8 + e
//   where co = c4*32 + nt*16 + lm, ch = ct*32 + lq*8 + e.   [verified rounds 6-8]
__global__ void prep_all(const float* __restrict__ x, const float* __restrict__ w,
                         unsigned short* __restrict__ xt, unsigned short* __restrict__ wt) {
    int b = blockIdx.x;
    int t = threadIdx.x;
    if (b >= NB * H) {                        // ---- weight part ----
        int idx = (b - NB * H) * 256 + t;
        if (idx < KK * COUT * CIN) {
            int e  = idx & 7;
            int lq = (idx >> 3) & 3;
            int lm = (idx >> 5) & 15;
            int ct = (idx >> 9) & 3;
            int nt = (idx >> 11) & 1;
            int c4 = (idx >> 12) & 3;
            int kk = idx >> 14;
            int co = (c4 << 5) + (nt << 4) + lm;
            int ch = (ct << 5) + (lq << 3) + e;
            wt[idx] = f2bf(w[(co * CIN + ch) * KK + kk]);
        }
        return;
    }
    // ---- x-transpose part: one (n,y) row per block; n = b&7 matches XCD map ----
    __shared__ float tile[CIN][W + 4];
    int n = b & 7, y = b >> 3;
    const float* src = x + ((size_t)n * CIN * H + y) * W;
    #pragma unroll
    for (int it = 0; it < 8; ++it) {
        int idx = it * 256 + t;               // 0..2047 float4s
        int c  = idx >> 4;
        int x4 = (idx & 15) << 2;
        int xs = (x4 + ((c >> 5) << 4)) & 63; // rotate-swizzle per 32-ch group
        *(float4*)&tile[c][xs] = *(const float4*)(src + (size_t)c * H * W + x4);
    }
    __syncthreads();
    int xp = t >> 2;                          // x position 0..63
    int cbch = (t & 3) << 5;                  // channel base (32-ch chunk)
    int xr = (xp + ((cbch >> 5) << 4)) & 63;
    unsigned short* dst = xt + (((size_t)(n * H + y) * W + xp) * CIN + cbch);
    unsigned rr[16];
    #pragma unroll
    for (int i = 0; i < 16; ++i)
        rr[i] = cvt_pk_bf16(tile[cbch + 2 * i][xr], tile[cbch + 2 * i + 1][xr]);
    #pragma unroll
    for (int i = 0; i < 4; ++i)
        ((uint4*)dst)[i] = make_uint4(rr[4*i], rr[4*i+1], rr[4*i+2], rr[4*i+3]);
}

struct GatherCtx {
    const unsigned short *c00, *c01, *c10, *c11;
    float w00, w01, w10, w11;
};

__device__ __forceinline__ GatherCtx gather_setup(float dy, float dx, int ho, int wo, int kk,
                                                  const unsigned short* xbase) {
    GatherCtx g;
    float py = (float)(ho - 1 + kk / 3) + dy;
    float px = (float)(wo - 1 + kk % 3) + dx;
    float y0f = floorf(py), x0f = floorf(px);
    float wy1 = py - y0f, wx1 = px - x0f;
    float wy0 = 1.f - wy1, wx0 = 1.f - wx1;
    int y0 = (int)y0f, x0 = (int)x0f;
    int y1 = y0 + 1, x1 = x0 + 1;
    bool vy0 = (unsigned)y0 < (unsigned)H, vy1 = (unsigned)y1 < (unsigned)H;
    bool vx0 = (unsigned)x0 < (unsigned)W, vx1 = (unsigned)x1 < (unsigned)W;
    g.w00 = (vy0 && vx0) ? wy0 * wx0 : 0.f;
    g.w01 = (vy0 && vx1) ? wy0 * wx1 : 0.f;
    g.w10 = (vy1 && vx0) ? wy1 * wx0 : 0.f;
    g.w11 = (vy1 && vx1) ? wy1 * wx1 : 0.f;
    int yc0 = min(max(y0, 0), H - 1), yc1 = min(max(y1, 0), H - 1);
    int xc0 = min(max(x0, 0), W - 1), xc1 = min(max(x1, 0), W - 1);
    const unsigned short* r0 = xbase + (size_t)yc0 * W * CIN;
    const unsigned short* r1 = xbase + (size_t)yc1 * W * CIN;
    g.c00 = r0 + xc0 * CIN;  g.c01 = r0 + xc1 * CIN;
    g.c10 = r1 + xc0 * CIN;  g.c11 = r1 + xc1 * CIN;
    return g;
}

// Fused kernel: one block per (n, ho); n = bid&7 (XCD-local). 512 threads = 8 waves.
__global__ __launch_bounds__(512, 4) void fused_main(
        const float* __restrict__ offs, const unsigned short* __restrict__ xt,
        const unsigned short* __restrict__ wt, unsigned short* __restrict__ S,
        float* __restrict__ out) {
    __shared__ __attribute__((aligned(16))) unsigned short samp[2][64][SROW];  // 34,816 B

    int b = blockIdx.x;
    int n = b & 7, ho = b >> 3;
    int t = threadIdx.x;
    int lane = t & 63, wv = t >> 6;
    int lm = lane & 15, lq = lane >> 4;

    // shared thread map for both phases: pos = t>>3 (0..63), 16-ch chunk = t&7
    int pos = t >> 3;
    int c16 = t & 7;
    int cb  = c16 << 4;

    // ---------------- phase A: sample all 9 taps -> S row (no barriers) ----------------
    const float* offp = offs + (size_t)n * 2 * KK * H * W + (size_t)ho * W + pos;
    const unsigned short* xb = xt + (size_t)n * H * W * CIN + cb;
    size_t srow = ((((size_t)(n * H + ho) * W + pos) * KK) << 7) + cb;   // element idx

    for (int tap = 0; tap < KK; ++tap) {
        float dy = offp[(size_t)(2 * tap) * H * W];
        float dx = offp[(size_t)(2 * tap + 1) * H * W];
        GatherCtx g = gather_setup(dy, dx, ho, pos, tap, xb);
        uint4 gv[8];
        #pragma unroll
        for (int j = 0; j < 2; ++j) {
            gv[4*j+0] = *(const uint4*)(g.c00 + 8*j);
            gv[4*j+1] = *(const uint4*)(g.c01 + 8*j);
            gv[4*j+2] = *(const uint4*)(g.c10 + 8*j);
            gv[4*j+3] = *(const uint4*)(g.c11 + 8*j);
        }
        unsigned rr[8];
        #pragma unroll
        for (int j = 0; j < 2; ++j) {
            const unsigned* a0 = (const unsigned*)&gv[4*j+0];
            const unsigned* a1 = (const unsigned*)&gv[4*j+1];
            const unsigned* a2 = (const unsigned*)&gv[4*j+2];
            const unsigned* a3 = (const unsigned*)&gv[4*j+3];
            #pragma unroll
            for (int i = 0; i < 4; ++i) {
                float v0 = g.w00*lo_f(a0[i]) + g.w01*lo_f(a1[i]) + g.w10*lo_f(a2[i]) + g.w11*lo_f(a3[i]);
                float v1 = g.w00*hi_f(a0[i]) + g.w01*hi_f(a1[i]) + g.w10*hi_f(a2[i]) + g.w11*hi_f(a3[i]);
                rr[4*j+i] = cvt_pk_bf16(v0, v1);
            }
        }
        unsigned short* sp = S + srow + ((size_t)tap << 7);
        *(uint4*)(sp)     = make_uint4(rr[0], rr[1], rr[2], rr[3]);
        *(uint4*)(sp + 8) = make_uint4(rr[4], rr[5], rr[6], rr[7]);
    }
    asm volatile("s_waitcnt vmcnt(0)" ::: "memory");   // own stores landed (L2)

    // ---------------- phase B: GEMM over taps (8 waves, wave = 64 pos x 16 co) ----------
    f32x4 acc[4];
    #pragma unroll
    for (int mt = 0; mt < 4; ++mt) acc[mt] = f32x4{0.f, 0.f, 0.f, 0.f};

    int slot = (lm << 2) + lq;
    // wave wv covers co block wv*16: wt2 base (tap*8 + wv)*2048 + slot*8; frag ct at +ct*512
    const unsigned short* wvbase = wt + ((size_t)wv << 11) + (slot << 3);
    const unsigned short* sme = S + srow;      // this thread's own 32B per tap

    // prologue: stage tap 0 (own-data L2 hit)
    {
        uint4 s0 = *(const uint4*)(sme);
        uint4 s1 = *(const uint4*)(sme + 8);
        unsigned short* ld = &samp[0][pos][cb];
        *(uint4*)(ld)     = s0;
        *(uint4*)(ld + 8) = s1;
    }
    __syncthreads();

    for (int tap = 0; tap < KK; ++tap) {
        uint4 nx0, nx1;
        if (tap < KK - 1) {
            const unsigned short* sr = sme + ((size_t)(tap + 1) << 7);
            nx0 = *(const uint4*)(sr);
            nx1 = *(const uint4*)(sr + 8);
        }
        // B-frags for this tap (verified wt2 layout), 4 x b128 per wave-lane
        const unsigned short* wkb = wvbase + ((size_t)(tap << 3) << 11);
        bf16x8 bW[4];
        #pragma unroll
        for (int ct = 0; ct < 4; ++ct)
            bW[ct] = *(const bf16x8*)(wkb + (ct << 9));

        #pragma unroll
        for (int ct = 0; ct < 4; ++ct) {
            bf16x8 a[4];
            #pragma unroll
            for (int mt = 0; mt < 4; ++mt)
                a[mt] = *(const bf16x8*)&samp[tap & 1][lm + (mt << 4)][(ct << 5) + (lq << 3)];
            #pragma unroll
            for (int mt = 0; mt < 4; ++mt)
                acc[mt] = __builtin_amdgcn_mfma_f32_16x16x32_bf16(a[mt], bW[ct], acc[mt], 0, 0, 0);
        }
        if (tap < KK - 1) {
            unsigned short* ld = &samp[(tap + 1) & 1][pos][cb];
            *(uint4*)(ld)     = nx0;
            *(uint4*)(ld + 8) = nx1;
        }
        __syncthreads();
    }

    // epilogue: D[m = mt*16 + lq*4 + j][n-col = lm] -> out[n][co][ho][wo], float4 over wo
    int co = (wv << 4) + lm;
    #pragma unroll
    for (int mt = 0; mt < 4; ++mt) {
        int wob = (mt << 4) + (lq << 2);
        *(f32x4*)(out + (((size_t)(n * COUT + co) * H + ho) * W + wob)) = acc[mt];
    }
}

extern "C" void kernel_launch(void* const* d_in, const int* in_sizes, int n_in,
                              void* d_out, int out_size, void* d_ws, size_t ws_size,
                              hipStream_t stream) {
    const float* x      = (const float*)d_in[0];   // (8,128,64,64)
    const float* offset = (const float*)d_in[1];   // (8,18,64,64)
    const float* weight = (const float*)d_in[2];   // (128,128,3,3)
    float* out = (float*)d_out;

    unsigned short* xt = (unsigned short*)d_ws;                                  // 8 MB
    unsigned short* wt = (unsigned short*)((char*)d_ws + 8388608);               // 288 KB
    unsigned short* S  = (unsigned short*)((char*)d_ws + 8683520);               // 75.5 MB

    int wblocks = (KK * COUT * CIN + 255) / 256;   // 576
    hipLaunchKernelGGL(prep_all, dim3(NB * H + wblocks), dim3(256), 0, stream,
                       x, weight, xt, wt);
    hipLaunchKernelGGL(fused_main, dim3(NB * H), dim3(512), 0, stream,
                       offset, xt, wt, S, out);
}

// Round 10
// 102.712 us; speedup vs baseline: 1.1355x; 1.0638x over previous
//
#include <hip/hip_runtime.h>

// Deformable conv (K=3, stride=1, pad=1, dil=1), N=8, Cin=Cout=128, H=W=64.
// v11: v10's fusion was right but routed the per-thread sample data through a 75.5MB
//   S buffer that does NOT fit L2 (9.4MB/XCD vs 4MB) -> 137MB HBM round-trip = the
//   whole 48us (FETCH 43MB / WRITE 90MB, VGPR=44). Fix: the same thread produces and
//   consumes those bytes, so keep them in REGISTERS: stash[9][8] dwords = 72 VGPR,
//   fully unrolled / statically indexed (rule #20).
//   - phase A: barrier-free 9-tap gather->blend chain (v10's win) into stash.
//   - phase B: per tap ds_write stash[tap] -> LDS dbuf (2xb128 from regs), 1 barrier
//     per tap, v10's verified 8-wave MFMA (wave = 64 pos x 16 co, wt2 B-frags).
//   - S eliminated; no vmcnt fence between phases; launch_bounds(512,2) = 256 VGPR
//     budget, 1 block/CU (spill-free beats occupancy here).
//   - keeps: XCD-local n=bid&7, cvt_pk_bf16, padded SROW, verified wt2 layout.
// ws: xt 8MB @0; wt2 288KB @8388608. Fully rewritten each launch.

#define H  64
#define W  64
#define CIN 128
#define COUT 128
#define NB 8
#define KK 9
#define SROW (CIN + 8)

typedef short bf16x8 __attribute__((ext_vector_type(8)));
typedef float f32x4  __attribute__((ext_vector_type(4)));

__device__ __forceinline__ unsigned short f2bf(float f) {
    unsigned u = __builtin_bit_cast(unsigned, f);
    u += 0x7FFFu + ((u >> 16) & 1u);          // round-nearest-even
    return (unsigned short)(u >> 16);
}
__device__ __forceinline__ unsigned cvt_pk_bf16(float lo, float hi) {
    unsigned r;
    asm("v_cvt_pk_bf16_f32 %0, %1, %2" : "=v"(r) : "v"(lo), "v"(hi));
    return r;                                  // low16 = bf16(lo), high16 = bf16(hi), RNE
}
__device__ __forceinline__ float lo_f(unsigned u) { return __builtin_bit_cast(float, u << 16); }
__device__ __forceinline__ float hi_f(unsigned u) { return __builtin_bit_cast(float, u & 0xFFFF0000u); }

// Merged prep: blocks [0, NB*H) transpose x (NCHW fp32 -> NHWC bf16), XCD-local (n = b&7);
// blocks [NB*H, NB*H+576): weight fp32 [co][c][kk] -> wt2 fragment-contiguous bf16:
//   wt2 flat idx = ((((kk*4 + c4)*2 + nt)*4 + ct)*64 + lm*4 + lq)*8 + e
//   where co = c4*32 + nt*16 + lm, ch = ct*32 + lq*8 + e.   [verified rounds 6-9]
__global__ void prep_all(const float* __restrict__ x, const float* __restrict__ w,
                         unsigned short* __restrict__ xt, unsigned short* __restrict__ wt) {
    int b = blockIdx.x;
    int t = threadIdx.x;
    if (b >= NB * H) {                        // ---- weight part ----
        int idx = (b - NB * H) * 256 + t;
        if (idx < KK * COUT * CIN) {
            int e  = idx & 7;
            int lq = (idx >> 3) & 3;
            int lm = (idx >> 5) & 15;
            int ct = (idx >> 9) & 3;
            int nt = (idx >> 11) & 1;
            int c4 = (idx >> 12) & 3;
            int kk = idx >> 14;
            int co = (c4 << 5) + (nt << 4) + lm;
            int ch = (ct << 5) + (lq << 3) + e;
            wt[idx] = f2bf(w[(co * CIN + ch) * KK + kk]);
        }
        return;
    }
    // ---- x-transpose part: one (n,y) row per block; n = b&7 matches XCD map ----
    __shared__ float tile[CIN][W + 4];
    int n = b & 7, y = b >> 3;
    const float* src = x + ((size_t)n * CIN * H + y) * W;
    #pragma unroll
    for (int it = 0; it < 8; ++it) {
        int idx = it * 256 + t;               // 0..2047 float4s
        int c  = idx >> 4;
        int x4 = (idx & 15) << 2;
        int xs = (x4 + ((c >> 5) << 4)) & 63; // rotate-swizzle per 32-ch group
        *(float4*)&tile[c][xs] = *(const float4*)(src + (size_t)c * H * W + x4);
    }
    __syncthreads();
    int xp = t >> 2;                          // x position 0..63
    int cbch = (t & 3) << 5;                  // channel base (32-ch chunk)
    int xr = (xp + ((cbch >> 5) << 4)) & 63;
    unsigned short* dst = xt + (((size_t)(n * H + y) * W + xp) * CIN + cbch);
    unsigned rr[16];
    #pragma unroll
    for (int i = 0; i < 16; ++i)
        rr[i] = cvt_pk_bf16(tile[cbch + 2 * i][xr], tile[cbch + 2 * i + 1][xr]);
    #pragma unroll
    for (int i = 0; i < 4; ++i)
        ((uint4*)dst)[i] = make_uint4(rr[4*i], rr[4*i+1], rr[4*i+2], rr[4*i+3]);
}

struct GatherCtx {
    const unsigned short *c00, *c01, *c10, *c11;
    float w00, w01, w10, w11;
};

__device__ __forceinline__ GatherCtx gather_setup(float dy, float dx, int ho, int wo, int kk,
                                                  const unsigned short* xbase) {
    GatherCtx g;
    float py = (float)(ho - 1 + kk / 3) + dy;
    float px = (float)(wo - 1 + kk % 3) + dx;
    float y0f = floorf(py), x0f = floorf(px);
    float wy1 = py - y0f, wx1 = px - x0f;
    float wy0 = 1.f - wy1, wx0 = 1.f - wx1;
    int y0 = (int)y0f, x0 = (int)x0f;
    int y1 = y0 + 1, x1 = x0 + 1;
    bool vy0 = (unsigned)y0 < (unsigned)H, vy1 = (unsigned)y1 < (unsigned)H;
    bool vx0 = (unsigned)x0 < (unsigned)W, vx1 = (unsigned)x1 < (unsigned)W;
    g.w00 = (vy0 && vx0) ? wy0 * wx0 : 0.f;
    g.w01 = (vy0 && vx1) ? wy0 * wx1 : 0.f;
    g.w10 = (vy1 && vx0) ? wy1 * wx0 : 0.f;
    g.w11 = (vy1 && vx1) ? wy1 * wx1 : 0.f;
    int yc0 = min(max(y0, 0), H - 1), yc1 = min(max(y1, 0), H - 1);
    int xc0 = min(max(x0, 0), W - 1), xc1 = min(max(x1, 0), W - 1);
    const unsigned short* r0 = xbase + (size_t)yc0 * W * CIN;
    const unsigned short* r1 = xbase + (size_t)yc1 * W * CIN;
    g.c00 = r0 + xc0 * CIN;  g.c01 = r0 + xc1 * CIN;
    g.c10 = r1 + xc0 * CIN;  g.c11 = r1 + xc1 * CIN;
    return g;
}

// Fused kernel: one block per (n, ho); n = bid&7 (XCD-local). 512 threads = 8 waves.
__global__ __launch_bounds__(512, 2) void fused_main(
        const float* __restrict__ offs, const unsigned short* __restrict__ xt,
        const unsigned short* __restrict__ wt, float* __restrict__ out) {
    __shared__ __attribute__((aligned(16))) unsigned short samp[2][64][SROW];  // 34,816 B

    int b = blockIdx.x;
    int n = b & 7, ho = b >> 3;
    int t = threadIdx.x;
    int lane = t & 63, wv = t >> 6;
    int lm = lane & 15, lq = lane >> 4;

    // shared thread map for both phases: pos = t>>3 (0..63), 16-ch chunk = t&7
    int pos = t >> 3;
    int cb  = (t & 7) << 4;

    // ---------------- phase A: sample all 9 taps -> stash (regs; no barriers) --------
    const float* offp = offs + (size_t)n * 2 * KK * H * W + (size_t)ho * W + pos;
    const unsigned short* xb = xt + (size_t)n * H * W * CIN + cb;

    unsigned stash[KK][8];                    // 72 VGPR, statically indexed (rule #20)
    #pragma unroll
    for (int tap = 0; tap < KK; ++tap) {
        float dy = offp[(size_t)(2 * tap) * H * W];
        float dx = offp[(size_t)(2 * tap + 1) * H * W];
        GatherCtx g = gather_setup(dy, dx, ho, pos, tap, xb);
        uint4 gv[8];
        #pragma unroll
        for (int j = 0; j < 2; ++j) {
            gv[4*j+0] = *(const uint4*)(g.c00 + 8*j);
            gv[4*j+1] = *(const uint4*)(g.c01 + 8*j);
            gv[4*j+2] = *(const uint4*)(g.c10 + 8*j);
            gv[4*j+3] = *(const uint4*)(g.c11 + 8*j);
        }
        #pragma unroll
        for (int j = 0; j < 2; ++j) {
            const unsigned* a0 = (const unsigned*)&gv[4*j+0];
            const unsigned* a1 = (const unsigned*)&gv[4*j+1];
            const unsigned* a2 = (const unsigned*)&gv[4*j+2];
            const unsigned* a3 = (const unsigned*)&gv[4*j+3];
            #pragma unroll
            for (int i = 0; i < 4; ++i) {
                float v0 = g.w00*lo_f(a0[i]) + g.w01*lo_f(a1[i]) + g.w10*lo_f(a2[i]) + g.w11*lo_f(a3[i]);
                float v1 = g.w00*hi_f(a0[i]) + g.w01*hi_f(a1[i]) + g.w10*hi_f(a2[i]) + g.w11*hi_f(a3[i]);
                stash[tap][4*j+i] = cvt_pk_bf16(v0, v1);
            }
        }
    }

    // ---------------- phase B: GEMM over taps (8 waves, wave = 64 pos x 16 co) --------
    f32x4 acc[4];
    #pragma unroll
    for (int mt = 0; mt < 4; ++mt) acc[mt] = f32x4{0.f, 0.f, 0.f, 0.f};

    int slot = (lm << 2) + lq;
    // wave wv covers co block wv*16: wt2 base (tap*8 + wv)*2048 + slot*8; frag ct at +ct*512
    const unsigned short* wvbase = wt + ((size_t)wv << 11) + (slot << 3);

    // prologue: stage tap 0 from regs
    {
        unsigned short* ld = &samp[0][pos][cb];
        *(uint4*)(ld)     = make_uint4(stash[0][0], stash[0][1], stash[0][2], stash[0][3]);
        *(uint4*)(ld + 8) = make_uint4(stash[0][4], stash[0][5], stash[0][6], stash[0][7]);
    }
    __syncthreads();

    #pragma unroll
    for (int tap = 0; tap < KK; ++tap) {
        if (tap < KK - 1) {                   // stage tap+1 into the other buffer
            unsigned short* ld = &samp[(tap + 1) & 1][pos][cb];
            *(uint4*)(ld)     = make_uint4(stash[tap+1][0], stash[tap+1][1],
                                           stash[tap+1][2], stash[tap+1][3]);
            *(uint4*)(ld + 8) = make_uint4(stash[tap+1][4], stash[tap+1][5],
                                           stash[tap+1][6], stash[tap+1][7]);
        }
        // B-frags for this tap (verified wt2 layout), 4 x b128 per wave-lane
        const unsigned short* wkb = wvbase + ((size_t)(tap << 3) << 11);
        bf16x8 bW[4];
        #pragma unroll
        for (int ct = 0; ct < 4; ++ct)
            bW[ct] = *(const bf16x8*)(wkb + (ct << 9));

        __builtin_amdgcn_s_setprio(1);
        #pragma unroll
        for (int ct = 0; ct < 4; ++ct) {
            bf16x8 a[4];
            #pragma unroll
            for (int mt = 0; mt < 4; ++mt)
                a[mt] = *(const bf16x8*)&samp[tap & 1][lm + (mt << 4)][(ct << 5) + (lq << 3)];
            #pragma unroll
            for (int mt = 0; mt < 4; ++mt)
                acc[mt] = __builtin_amdgcn_mfma_f32_16x16x32_bf16(a[mt], bW[ct], acc[mt], 0, 0, 0);
        }
        __builtin_amdgcn_s_setprio(0);
        __syncthreads();
    }

    // epilogue: D[m = mt*16 + lq*4 + j][n-col = lm] -> out[n][co][ho][wo], float4 over wo
    int co = (wv << 4) + lm;
    #pragma unroll
    for (int mt = 0; mt < 4; ++mt) {
        int wob = (mt << 4) + (lq << 2);
        *(f32x4*)(out + (((size_t)(n * COUT + co) * H + ho) * W + wob)) = acc[mt];
    }
}

extern "C" void kernel_launch(void* const* d_in, const int* in_sizes, int n_in,
                              void* d_out, int out_size, void* d_ws, size_t ws_size,
                              hipStream_t stream) {
    const float* x      = (const float*)d_in[0];   // (8,128,64,64)
    const float* offset = (const float*)d_in[1];   // (8,18,64,64)
    const float* weight = (const float*)d_in[2];   // (128,128,3,3)
    float* out = (float*)d_out;

    unsigned short* xt = (unsigned short*)d_ws;                                  // 8 MB
    unsigned short* wt = (unsigned short*)((char*)d_ws + 8388608);               // 288 KB

    int wblocks = (KK * COUT * CIN + 255) / 256;   // 576
    hipLaunchKernelGGL(prep_all, dim3(NB * H + wblocks), dim3(256), 0, stream,
                       x, weight, xt, wt);
    hipLaunchKernelGGL(fused_main, dim3(NB * H), dim3(512), 0, stream,
                       offset, xt, wt, out);
}